// Round 7
// baseline (426.156 us; speedup 1.0000x reference)
//
#include <hip/hip_runtime.h>

typedef __bf16 bf16_t;
typedef __bf16 bf16x8 __attribute__((ext_vector_type(8)));
typedef __bf16 bf16x4 __attribute__((ext_vector_type(4)));
typedef __bf16 bf16x2 __attribute__((ext_vector_type(2)));
typedef float  f32x4  __attribute__((ext_vector_type(4)));

#define DEVINL __device__ __forceinline__

static constexpr size_t N_PIX = 16384;

// ---------------- per-batch workspace layout (bytes) ----------------
static constexpr size_t OFF_Q   = 0;                                   // Qf f32 [512][N] (exact-ish q for attn)
static constexpr size_t SZ_Q    = (size_t)512 * N_PIX * 4;             // 33.55 MB
static constexpr size_t OFF_QB  = OFF_Q + SZ_Q;                        // Qb bf16 [512][N] (for dwpw)
static constexpr size_t SZ_QB   = (size_t)512 * N_PIX * 2;             // 16.78 MB
static constexpr size_t OFF_KV  = OFF_QB + SZ_QB;                      // KV bf16 [1024][N]: rows 0..511 K, 512..1023 V
static constexpr size_t SZ_KV   = (size_t)1024 * N_PIX * 2;            // 33.55 MB
static constexpr size_t OFF_Y   = OFF_KV + SZ_KV;                      // y bf16 [1536][N] (interleaved 24/head)
static constexpr size_t SZ_Y    = (size_t)1536 * N_PIX * 2;            // 50.33 MB
static constexpr size_t OFF_ATT = OFF_Y + SZ_Y;                        // attT bf16 [N][1024]; xTh/xTl aliased
static constexpr size_t SZ_ATT  = (size_t)N_PIX * 1024 * 2;            // 33.55 MB
static constexpr size_t OFF_XTH = OFF_ATT;                             // xT_hi bf16 [N][512] (dead after qkv GEMM)
static constexpr size_t OFF_XTL = OFF_ATT + (size_t)N_PIX * 512 * 2;   // xT_lo bf16 [N][512]
static constexpr size_t OFF_WQA = OFF_ATT + SZ_ATT;                    // wqA bf16 [512][1536] = [hi|lo|hi]
static constexpr size_t SZ_WQA  = (size_t)512 * 1536 * 2;
static constexpr size_t OFF_WKV = OFF_WQA + SZ_WQA;                    // wkv bf16 [1024][512]
static constexpr size_t SZ_WKV  = (size_t)1024 * 512 * 2;
static constexpr size_t OFF_WP  = OFF_WKV + SZ_WKV;                    // wpb bf16 [512][1024], pre-scaled by bn inv
static constexpr size_t SZ_WP   = (size_t)512 * 1024 * 2;
static constexpr size_t OFF_VK  = OFF_WP + SZ_WP;                      // vk f32 [128][72]
static constexpr size_t SZ_VK   = (size_t)128 * 72 * 4;
static constexpr size_t OFF_VKP = OFF_VK + SZ_VK;                      // vk partials f32 [128][8][72]
static constexpr size_t SZ_VKP  = (size_t)128 * 8 * 72 * 4;
static constexpr size_t OFF_BNA = OFF_VKP + SZ_VKP;                    // f32[512]
static constexpr size_t OFF_ZP  = OFF_BNA + 2048;                      // 64B zero page
static constexpr size_t WS_NEEDED = OFF_ZP + 64;                       // ~171.8 MB

// ---------------- helpers ----------------
DEVINL void gload16(const bf16_t* g, bf16_t* l) {
  // async global->LDS, 16B per lane; LDS dest = wave-uniform base + lane*16, global addr per-lane
  __builtin_amdgcn_global_load_lds((const __attribute__((address_space(1))) void*)g,
                                   (__attribute__((address_space(3))) void*)l, 16, 0, 0);
}

// ---------------- K0a: transpose x (f32 [512][N]) -> xT_hi/xT_lo (bf16 [N][512]) ----------------
__global__ __launch_bounds__(256)
void xpose_kernel(const float* __restrict__ x, bf16_t* __restrict__ xTh, bf16_t* __restrict__ xTl) {
  __shared__ float t[32][33];
  const int n0 = blockIdx.x * 32, c0 = blockIdx.y * 32;
  const int tx = threadIdx.x & 31, ty = threadIdx.x >> 5;  // ty 0..7
#pragma unroll
  for (int r = 0; r < 4; ++r)
    t[ty + r * 8][tx] = x[(size_t)(c0 + ty + r * 8) * N_PIX + n0 + tx];  // t[c][n]
  __syncthreads();
  // write: 256 threads -> 256 bf16x8 chunks (32 n-rows x 4 col-groups x 2 planes)
  const int nl = threadIdx.x >> 3, sub = threadIdx.x & 7;
  const int c8 = (sub & 3) * 8, plane = sub >> 2;
  bf16x8 o;
#pragma unroll
  for (int k = 0; k < 8; ++k) {
    const float v = t[c8 + k][nl];
    if (plane == 0) {
      o[k] = (bf16_t)v;
    } else {
      const bf16_t hi = (bf16_t)v;
      o[k] = (bf16_t)(v - (float)hi);
    }
  }
  bf16_t* dst = plane ? xTl : xTh;
  *(bf16x8*)&dst[(size_t)(n0 + nl) * 512 + c0 + c8] = o;
}

// ---------------- K0b: build wqA [hi|lo|hi], wkv, scaled wpb, bna, zero page ----------------
static constexpr int PREP_W1 = 512 * 1536;           // wqA
static constexpr int PREP_W2 = 1024 * 512;           // wkv
static constexpr int PREP_W3 = 512 * 1024;           // wpb
static constexpr int PREP_TOT = PREP_W1 + PREP_W2 + PREP_W3 + 512 + 16;
__global__ __launch_bounds__(256)
void prep_kernel(const float* __restrict__ wq, const float* __restrict__ wp,
                 const float* __restrict__ gam, const float* __restrict__ bet,
                 const float* __restrict__ mu, const float* __restrict__ va,
                 bf16_t* __restrict__ wqA, bf16_t* __restrict__ wkv, bf16_t* __restrict__ wpb,
                 float* __restrict__ bna, float* __restrict__ zp) {
  const int i = blockIdx.x * 256 + threadIdx.x;
  if (i < PREP_W1) {
    const int r = i / 1536, c = i - r * 1536;
    const int o = (r >> 3) * 24 + (r & 7);  // q row in original w_qkv
    bf16_t out;
    if (c < 512) {
      out = (bf16_t)wq[o * 512 + c];
    } else if (c < 1024) {
      const float v = wq[o * 512 + c - 512];
      const bf16_t hi = (bf16_t)v;
      out = (bf16_t)(v - (float)hi);
    } else {
      out = (bf16_t)wq[o * 512 + c - 1024];
    }
    wqA[i] = out;
  } else if (i < PREP_W1 + PREP_W2) {
    const int j = i - PREP_W1;
    const int r = j >> 9, c = j & 511;
    const int h = (r & 511) >> 3;
    const int jj = (r < 512 ? 8 : 16) + (r & 7);
    wkv[j] = (bf16_t)wq[(h * 24 + jj) * 512 + c];
  } else if (i < PREP_W1 + PREP_W2 + PREP_W3) {
    const int j = i - PREP_W1 - PREP_W2;
    const int m = j >> 10;
    const float inv = gam[m] / sqrtf(va[m] + 1e-5f);
    wpb[j] = (bf16_t)(wp[j] * inv);
  } else if (i < PREP_W1 + PREP_W2 + PREP_W3 + 512) {
    const int k = i - PREP_W1 - PREP_W2 - PREP_W3;
    const float inv = gam[k] / sqrtf(va[k] + 1e-5f);
    bna[k] = bet[k] - mu[k] * inv;
  } else if (i < PREP_TOT) {
    zp[i - (PREP_W1 + PREP_W2 + PREP_W3 + 512)] = 0.f;
  }
}

// ---------------- K1: merged q/kv GEMM, 128x128 tile, BK=64, XOR-swizzled LDS ----------------
__global__ __launch_bounds__(256, 4)
void gemm_qkv_kernel(const bf16_t* __restrict__ wqA, const bf16_t* __restrict__ wkv,
                     const bf16_t* __restrict__ xTh, const bf16_t* __restrict__ xTl,
                     float* __restrict__ Qf, bf16_t* __restrict__ Qb, bf16_t* __restrict__ KV) {
  __shared__ __align__(16) bf16_t As[128 * 64];
  __shared__ __align__(16) bf16_t Bs[128 * 64];
  const int tid = threadIdx.x, wid = tid >> 6, lane = tid & 63;
  const int fr = lane & 15, fg = lane >> 4;
  const int wm = (wid >> 1) * 64, wn = (wid & 1) * 64;
  const int by = blockIdx.y;
  const bool isQ = by < 4;
  const int m0 = (isQ ? by : by - 4) * 128;
  const int n0 = blockIdx.x * 128;
  const int KA = isQ ? 1536 : 512;
  const bf16_t* Aptr = isQ ? wqA + (size_t)m0 * 1536 : wkv + (size_t)m0 * 512;
  const int srow = tid >> 3;                              // 0..31 (LDS row mod 32)
  const int soff = (((tid & 7) ^ (srow & 7)) * 8);        // pre-swizzled global chunk

  f32x4 acc[4][4] = {};

  for (int kk = 0; kk < KA; kk += 64) {
    const bf16_t* Bpl;
    int bcol;
    if (isQ) {
      Bpl  = (kk < 1024) ? xTh : xTl;
      bcol = (kk < 1024) ? (kk & 511) : (kk - 1024);
    } else {
      Bpl = xTh; bcol = kk;
    }
    __syncthreads();  // prev iter's LDS reads done
#pragma unroll
    for (int r = 0; r < 4; ++r) {
      gload16(Aptr + (size_t)(srow + 32 * r) * KA + kk + soff, As + (wid * 8 + 32 * r) * 64);
      gload16(Bpl + (size_t)(n0 + srow + 32 * r) * 512 + bcol + soff, Bs + (wid * 8 + 32 * r) * 64);
    }
    __syncthreads();  // drains vmcnt(0)
#pragma unroll
    for (int ks = 0; ks < 2; ++ks) {
      bf16x8 af[4], bfr[4];
#pragma unroll
      for (int i = 0; i < 4; ++i)
        af[i]  = *(const bf16x8*)&As[(wm + i * 16 + fr) * 64 + (((ks * 4 + fg) ^ (fr & 7)) * 8)];
#pragma unroll
      for (int j = 0; j < 4; ++j)
        bfr[j] = *(const bf16x8*)&Bs[(wn + j * 16 + fr) * 64 + (((ks * 4 + fg) ^ (fr & 7)) * 8)];
#pragma unroll
      for (int i = 0; i < 4; ++i)
#pragma unroll
        for (int j = 0; j < 4; ++j)
          acc[i][j] = __builtin_amdgcn_mfma_f32_16x16x32_bf16(af[i], bfr[j], acc[i][j], 0, 0, 0);
    }
  }

#pragma unroll
  for (int i = 0; i < 4; ++i)
#pragma unroll
    for (int r = 0; r < 4; ++r) {
      const int m = m0 + wm + i * 16 + fg * 4 + r;
#pragma unroll
      for (int j = 0; j < 4; ++j) {
        const int n = n0 + wn + j * 16 + fr;
        const float v = acc[i][j][r];
        if (isQ) {
          Qf[(size_t)m * N_PIX + n] = v;
          Qb[(size_t)m * N_PIX + n] = (bf16_t)v;
        } else {
          KV[(size_t)m * N_PIX + n] = (bf16_t)v;
        }
      }
    }
}

// ---------------- K5: proj GEMM (BN folded into A; epilogue +bna), BK=64, swizzled ----------------
__global__ __launch_bounds__(256, 4)
void gemm_proj_kernel(const bf16_t* __restrict__ A, const bf16_t* __restrict__ B,
                      float* __restrict__ Cout, const float* __restrict__ bna) {
  __shared__ __align__(16) bf16_t As[128 * 64];
  __shared__ __align__(16) bf16_t Bs[128 * 64];
  const int tid = threadIdx.x, wid = tid >> 6, lane = tid & 63;
  const int fr = lane & 15, fg = lane >> 4;
  const int wm = (wid >> 1) * 64, wn = (wid & 1) * 64;
  const int m0 = blockIdx.y * 128, n0 = blockIdx.x * 128;
  const int srow = tid >> 3;
  const int soff = (((tid & 7) ^ (srow & 7)) * 8);
  const bf16_t* Ab = A + (size_t)m0 * 1024;
  const bf16_t* Bb = B + (size_t)n0 * 1024;

  f32x4 acc[4][4] = {};

  for (int kk = 0; kk < 1024; kk += 64) {
    __syncthreads();
#pragma unroll
    for (int r = 0; r < 4; ++r) {
      gload16(Ab + (size_t)(srow + 32 * r) * 1024 + kk + soff, As + (wid * 8 + 32 * r) * 64);
      gload16(Bb + (size_t)(srow + 32 * r) * 1024 + kk + soff, Bs + (wid * 8 + 32 * r) * 64);
    }
    __syncthreads();
#pragma unroll
    for (int ks = 0; ks < 2; ++ks) {
      bf16x8 af[4], bfr[4];
#pragma unroll
      for (int i = 0; i < 4; ++i)
        af[i]  = *(const bf16x8*)&As[(wm + i * 16 + fr) * 64 + (((ks * 4 + fg) ^ (fr & 7)) * 8)];
#pragma unroll
      for (int j = 0; j < 4; ++j)
        bfr[j] = *(const bf16x8*)&Bs[(wn + j * 16 + fr) * 64 + (((ks * 4 + fg) ^ (fr & 7)) * 8)];
#pragma unroll
      for (int i = 0; i < 4; ++i)
#pragma unroll
        for (int j = 0; j < 4; ++j)
          acc[i][j] = __builtin_amdgcn_mfma_f32_16x16x32_bf16(af[i], bfr[j], acc[i][j], 0, 0, 0);
    }
  }

#pragma unroll
  for (int i = 0; i < 4; ++i)
#pragma unroll
    for (int r = 0; r < 4; ++r) {
      const int m = m0 + wm + i * 16 + fg * 4 + r;
      const float sh = bna[m];
#pragma unroll
      for (int j = 0; j < 4; ++j)
        Cout[(size_t)m * N_PIX + n0 + wn + j * 16 + fr] = acc[i][j][r] + sh;
    }
}

// ---------------- K2: fused dw 5x5 (pad 2) + grouped 1x1; double-buffered 4-tile pipeline ----------------
// group g (0..191): typ=g%3 (0:q from Qb, 1:k, 2:v from KV), head=g/3
// block: 32-row strip x 128 cols as 4 tiles of 16x64; stage(t+1) overlaps compute(t)
__global__ __launch_bounds__(256)
void dwpw_kernel(const bf16_t* __restrict__ Qb, const bf16_t* __restrict__ KV,
                 const float* __restrict__ wdw, const float* __restrict__ wpw,
                 const bf16_t* __restrict__ zp, bf16_t* __restrict__ y) {
  const int g = blockIdx.y;
  const int typ = g % 3, head = g / 3;
  const int r0 = blockIdx.x * 32;
  const int tid = threadIdx.x, wid = tid >> 6, lane = tid & 63;
  __shared__ __align__(16) bf16_t sbuf[2][8][20][80];   // 51.2 KB
  __shared__ float swd[8][25];
  __shared__ float swp[8][8];
  if (tid < 200) swd[tid / 25][tid % 25] = wdw[(g * 8 + tid / 25) * 25 + tid % 25];
  if (tid < 64)  swp[tid >> 3][tid & 7] = wpw[(g * 8 + (tid >> 3)) * 8 + (tid & 7)];
  const bf16_t* plane = (typ == 0) ? (Qb + (size_t)head * 8 * N_PIX)
                                   : (KV + (size_t)((typ == 2 ? 512 : 0) + head * 8) * N_PIX);

  // stage tile t into buffer buf: 1600 16B chunks -> [ch][row][c6*8..+7]
  auto stage = [&](int t, int buf) {
    const int ty0 = r0 + (t >> 1) * 16, tx0 = (t & 1) * 64;
    bf16_t* sf = &sbuf[buf][0][0][0];
    for (int base = wid * 64; base < 1600; base += 256) {
      const int id  = base + lane;
      const int ch  = id / 200;
      const int rem = id - ch * 200;
      const int row = rem / 10;
      const int c6  = rem - row * 10;
      const int gy  = ty0 + row - 2;
      const int gx  = tx0 + c6 * 8 - 8;
      const bool ok = ((unsigned)gy < 128u) && ((unsigned)gx < 128u);
      const bf16_t* src = ok ? (plane + (size_t)ch * N_PIX + gy * 128 + gx) : zp;
      gload16(src, sf + (size_t)base * 8);
    }
  };

  stage(0, 0);
  __syncthreads();  // compiler drains vmcnt(0) before barrier

  const int px4 = (tid & 15) * 4, py = tid >> 4;  // 4 px per thread, 16 rows
#pragma unroll
  for (int t = 0; t < 4; ++t) {
    if (t < 3) stage(t + 1, (t + 1) & 1);  // async: flies during compute below
    const int ty0 = r0 + (t >> 1) * 16, tx0 = (t & 1) * 64;
    const int cb = t & 1;
    float dwres[8][4];
#pragma unroll
    for (int ch = 0; ch < 8; ++ch) {
      float o0 = 0.f, o1 = 0.f, o2 = 0.f, o3 = 0.f;
#pragma unroll
      for (int di = 0; di < 5; ++di) {
        bf16x4 a0 = *(const bf16x4*)&sbuf[cb][ch][py + di][px4 + 4];
        bf16x4 a1 = *(const bf16x4*)&sbuf[cb][ch][py + di][px4 + 8];
        bf16x4 a2 = *(const bf16x4*)&sbuf[cb][ch][py + di][px4 + 12];
        float vv[12] = {(float)a0[0], (float)a0[1], (float)a0[2], (float)a0[3],
                        (float)a1[0], (float)a1[1], (float)a1[2], (float)a1[3],
                        (float)a2[0], (float)a2[1], (float)a2[2], (float)a2[3]};
#pragma unroll
        for (int dj = 0; dj < 5; ++dj) {
          const float w = swd[ch][di * 5 + dj];
          o0 += vv[dj + 2] * w; o1 += vv[dj + 3] * w;
          o2 += vv[dj + 4] * w; o3 += vv[dj + 5] * w;
        }
      }
      dwres[ch][0] = o0; dwres[ch][1] = o1; dwres[ch][2] = o2; dwres[ch][3] = o3;
    }
#pragma unroll
    for (int oc = 0; oc < 8; ++oc) {
      float o[4] = {0.f, 0.f, 0.f, 0.f};
#pragma unroll
      for (int ic = 0; ic < 8; ++ic) {
        const float w = swp[oc][ic];
#pragma unroll
        for (int u = 0; u < 4; ++u) o[u] += dwres[ic][u] * w;
      }
      bf16x4 ov;
#pragma unroll
      for (int u = 0; u < 4; ++u) ov[u] = (bf16_t)o[u];
      *(bf16x4*)&y[(size_t)(8 * g + oc) * N_PIX + (ty0 + py) * 128 + tx0 + px4] = ov;
    }
    if (t < 3) __syncthreads();  // drains stage(t+1) DMA; all waves done reading sbuf[cb]
  }
}

// ---------------- K3a: per-slice partial vk[d][e] = sum_n v_d * relu(k_e) (+ k-sum row) ----------------
__global__ __launch_bounds__(256)
void vk_partial_kernel(const bf16_t* __restrict__ KV, const bf16_t* __restrict__ yb,
                       float* __restrict__ part) {
  const int h = blockIdx.y, s = blockIdx.x;  // s: 0..7 pixel slices
  const bf16_t *kb, *vb;
  if (h < 64) {
    kb = KV + (size_t)(h * 8) * N_PIX;
    vb = KV + (size_t)(512 + h * 8) * N_PIX;
  } else {
    kb = yb + (size_t)(24 * (h - 64) + 8) * N_PIX;
    vb = yb + (size_t)(24 * (h - 64) + 16) * N_PIX;
  }
  float a[8][8] = {};
  float ak[8] = {};
  const int p0 = s * 2048 + (int)threadIdx.x * 4;
  for (int it = 0; it < 2; ++it) {
    const int p = p0 + it * 1024;
    float kq[8][4], vq[8][4];
#pragma unroll
    for (int e = 0; e < 8; ++e) {
      bf16x4 kk = *(const bf16x4*)&kb[(size_t)e * N_PIX + p];
#pragma unroll
      for (int u = 0; u < 4; ++u) kq[e][u] = fmaxf(0.f, (float)kk[u]);
    }
#pragma unroll
    for (int d = 0; d < 8; ++d) {
      bf16x4 vv = *(const bf16x4*)&vb[(size_t)d * N_PIX + p];
#pragma unroll
      for (int u = 0; u < 4; ++u) vq[d][u] = (float)vv[u];
    }
#pragma unroll
    for (int d = 0; d < 8; ++d)
#pragma unroll
      for (int e = 0; e < 8; ++e)
#pragma unroll
        for (int u = 0; u < 4; ++u) a[d][e] += vq[d][u] * kq[e][u];
#pragma unroll
    for (int e = 0; e < 8; ++e)
#pragma unroll
      for (int u = 0; u < 4; ++u) ak[e] += kq[e][u];
  }
  __shared__ float red[4][72];
  const int lane = threadIdx.x & 63, wid = threadIdx.x >> 6;
#pragma unroll
  for (int i = 0; i < 72; ++i) {
    float v = (i < 64) ? a[i >> 3][i & 7] : ak[i - 64];
    v += __shfl_xor(v, 32); v += __shfl_xor(v, 16); v += __shfl_xor(v, 8);
    v += __shfl_xor(v, 4);  v += __shfl_xor(v, 2);  v += __shfl_xor(v, 1);
    if (lane == 0) red[wid][i] = v;
  }
  __syncthreads();
  if (threadIdx.x < 72) {
    const float sum_ = red[0][threadIdx.x] + red[1][threadIdx.x] + red[2][threadIdx.x] + red[3][threadIdx.x];
    part[((size_t)h * 8 + s) * 72 + threadIdx.x] = sum_;
  }
}

// ---------------- K3b: deterministic reduce of 8 slices ----------------
__global__ __launch_bounds__(128)
void vk_reduce_kernel(const float* __restrict__ part, float* __restrict__ vk) {
  const int h = blockIdx.x;  // 0..127
  const int i = threadIdx.x;
  if (i < 72) {
    float s = 0.f;
#pragma unroll
    for (int t = 0; t < 8; ++t) s += part[((size_t)h * 8 + t) * 72 + i];
    vk[(size_t)h * 72 + i] = s;
  }
}

// ---------------- K4: attention apply -> attT bf16 [N][1024] ----------------
__global__ __launch_bounds__(256)
void attn_kernel(const float* __restrict__ Qf, const bf16_t* __restrict__ yb,
                 const float* __restrict__ vk, bf16_t* __restrict__ attT) {
  const int n0 = blockIdx.x * 32;
  const int tid = threadIdx.x;
  const int px = tid & 31, hl = tid >> 5;  // hl: 0..7
  __shared__ __align__(16) bf16_t att_s[32 * 512];
  __shared__ float vk_s[576];
  for (int grp = 0; grp < 2; ++grp) {
    for (int hg = 0; hg < 8; ++hg) {
      __syncthreads();  // protect vk_s (and att_s on grp switch)
      for (int i = tid; i < 576; i += 256)
        vk_s[i] = vk[((size_t)grp * 64 + hg * 8) * 72 + i];
      __syncthreads();
      const int hh = hg * 8 + hl;  // head within half (0..63)
      float q[8];
      if (grp == 0) {
        const float* plane = Qf + (size_t)(hh * 8) * N_PIX + n0 + px;
#pragma unroll
        for (int e = 0; e < 8; ++e) q[e] = fmaxf(0.f, plane[(size_t)e * N_PIX]);
      } else {
        const bf16_t* plane = yb + (size_t)(24 * hh) * N_PIX + n0 + px;
#pragma unroll
        for (int e = 0; e < 8; ++e) q[e] = fmaxf(0.f, (float)plane[(size_t)e * N_PIX]);
      }
      float den = 1e-15f;
#pragma unroll
      for (int e = 0; e < 8; ++e) den += vk_s[hl * 72 + 64 + e] * q[e];
      const float rden = 1.0f / den;
      bf16x8 r8;
#pragma unroll
      for (int d = 0; d < 8; ++d) {
        float num = 0.f;
#pragma unroll
        for (int e = 0; e < 8; ++e) num += vk_s[hl * 72 + d * 8 + e] * q[e];
        r8[d] = (bf16_t)(num * rden);
      }
      const int chunk = hg * 8 + hl;  // 16B chunk index within half-row
      *(bf16x8*)&att_s[px * 512 + ((chunk ^ (px & 7)) << 3)] = r8;
    }
    __syncthreads();
    bf16_t* dst = attT + (size_t)n0 * 1024 + grp * 512;
    for (int i = tid; i < 2048; i += 256) {
      const int r = i >> 6, cc = i & 63;
      bf16x8 v = *(const bf16x8*)&att_s[r * 512 + (((cc ^ (r & 7))) << 3)];
      *(bf16x8*)&dst[(size_t)r * 1024 + cc * 8] = v;
    }
  }
}

// ---------------- launch ----------------
extern "C" void kernel_launch(void* const* d_in, const int* in_sizes, int n_in,
                              void* d_out, int out_size, void* d_ws, size_t ws_size,
                              hipStream_t stream) {
  if (ws_size < WS_NEEDED) return;  // need ~172 MB scratch
  const float* x      = (const float*)d_in[0];
  const float* w_qkv  = (const float*)d_in[1];
  const float* w_dw   = (const float*)d_in[2];
  const float* w_pw   = (const float*)d_in[3];
  const float* w_proj = (const float*)d_in[4];
  const float* gam    = (const float*)d_in[5];
  const float* bet    = (const float*)d_in[6];
  const float* mu     = (const float*)d_in[7];
  const float* va     = (const float*)d_in[8];

  char* w = (char*)d_ws;
  float*  Qf   = (float*)(w + OFF_Q);
  bf16_t* Qb   = (bf16_t*)(w + OFF_QB);
  bf16_t* KV   = (bf16_t*)(w + OFF_KV);
  bf16_t* yb   = (bf16_t*)(w + OFF_Y);
  bf16_t* xTh  = (bf16_t*)(w + OFF_XTH);  // aliased with attT (dead after K1)
  bf16_t* xTl  = (bf16_t*)(w + OFF_XTL);
  bf16_t* attT = (bf16_t*)(w + OFF_ATT);
  bf16_t* wqA  = (bf16_t*)(w + OFF_WQA);
  bf16_t* wkv  = (bf16_t*)(w + OFF_WKV);
  bf16_t* wpb  = (bf16_t*)(w + OFF_WP);
  float*  vk   = (float*)(w + OFF_VK);
  float*  part = (float*)(w + OFF_VKP);
  float*  bna  = (float*)(w + OFF_BNA);
  float*  zp   = (float*)(w + OFF_ZP);

  dim3 blk(256);
  // weights + BN fold + zero page (once)
  prep_kernel<<<dim3((PREP_TOT + 255) / 256), blk, 0, stream>>>(
      w_qkv, w_proj, gam, bet, mu, va, wqA, wkv, wpb, bna, zp);

  for (int b = 0; b < 2; ++b) {
    const float* xb = x + (size_t)b * 512 * N_PIX;
    float* outb = (float*)d_out + (size_t)b * 512 * N_PIX;
    // K0a: x -> xT hi/lo bf16
    xpose_kernel<<<dim3(512, 16), blk, 0, stream>>>(xb, xTh, xTl);
    // K1: merged q (3-term via K=1536) + kv GEMM
    gemm_qkv_kernel<<<dim3(128, 12), blk, 0, stream>>>(wqA, wkv, xTh, xTl, Qf, Qb, KV);
    // K2: fused dw 5x5 + grouped pw -> y (interleaved bf16), pipelined 4-tile blocks
    dwpw_kernel<<<dim3(4, 192), blk, 0, stream>>>(Qb, KV, w_dw, w_pw, (const bf16_t*)zp, yb);
    // K3: vk accumulation (partials, then deterministic reduce)
    vk_partial_kernel<<<dim3(8, 128), blk, 0, stream>>>(KV, yb, part);
    vk_reduce_kernel<<<dim3(128), dim3(128), 0, stream>>>(part, vk);
    // K4: attention apply -> attT
    attn_kernel<<<dim3(512), blk, 0, stream>>>(Qf, yb, vk, attT);
    // K5: out = wpb * att + bna (M=512, K=1024), f32 out
    gemm_proj_kernel<<<dim3(128, 4), blk, 0, stream>>>(wpb, attT, outb, bna);
  }
}

// Round 8
// 369.040 us; speedup vs baseline: 1.1548x; 1.1548x over previous
//
#include <hip/hip_runtime.h>

typedef __bf16 bf16_t;
typedef __bf16 bf16x8 __attribute__((ext_vector_type(8)));
typedef __bf16 bf16x4 __attribute__((ext_vector_type(4)));
typedef __bf16 bf16x2 __attribute__((ext_vector_type(2)));
typedef float  f32x4  __attribute__((ext_vector_type(4)));

#define DEVINL __device__ __forceinline__

static constexpr size_t N_PIX = 16384;

// ---------------- per-batch workspace layout (bytes) ----------------
static constexpr size_t OFF_QB  = 0;                                   // Qb bf16 [512][N] (pre-relu, dwpw input)
static constexpr size_t SZ_QB   = (size_t)512 * N_PIX * 2;             // 16.78 MB
static constexpr size_t OFF_QR  = OFF_QB + SZ_QB;                      // Qr bf16 [512][N] (relu'd, attn input)
static constexpr size_t SZ_QR   = SZ_QB;
static constexpr size_t OFF_KV  = OFF_QR + SZ_QR;                      // KV bf16 [1024][N]: rows 0..511 K, 512..1023 V
static constexpr size_t SZ_KV   = (size_t)1024 * N_PIX * 2;            // 33.55 MB
static constexpr size_t OFF_Y   = OFF_KV + SZ_KV;                      // y bf16 [1536][N] (interleaved 24/head)
static constexpr size_t SZ_Y    = (size_t)1536 * N_PIX * 2;            // 50.33 MB
static constexpr size_t OFF_ATT = OFF_Y + SZ_Y;                        // attT bf16 [N][1024]; xTh/xTl aliased
static constexpr size_t SZ_ATT  = (size_t)N_PIX * 1024 * 2;            // 33.55 MB
static constexpr size_t OFF_XTH = OFF_ATT;                             // xT_hi bf16 [N][512] (dead after qkv GEMM)
static constexpr size_t OFF_XTL = OFF_ATT + (size_t)N_PIX * 512 * 2;   // xT_lo bf16 [N][512]
static constexpr size_t OFF_WQA = OFF_ATT + SZ_ATT;                    // wqA bf16 [512][1536] = [hi|lo|hi]
static constexpr size_t SZ_WQA  = (size_t)512 * 1536 * 2;
static constexpr size_t OFF_WKV = OFF_WQA + SZ_WQA;                    // wkv bf16 [1024][512]
static constexpr size_t SZ_WKV  = (size_t)1024 * 512 * 2;
static constexpr size_t OFF_WP  = OFF_WKV + SZ_WKV;                    // wpb bf16 [512][1024], pre-scaled by bn inv
static constexpr size_t SZ_WP   = (size_t)512 * 1024 * 2;
static constexpr size_t OFF_VK  = OFF_WP + SZ_WP;                      // vk f32 [128][72]
static constexpr size_t SZ_VK   = (size_t)128 * 72 * 4;
static constexpr size_t OFF_VKP = OFF_VK + SZ_VK;                      // vk partials f32 [128][8][72]
static constexpr size_t SZ_VKP  = (size_t)128 * 8 * 72 * 4;
static constexpr size_t OFF_BNA = OFF_VKP + SZ_VKP;                    // f32[512]
static constexpr size_t OFF_ZP  = OFF_BNA + 2048;                      // 64B zero page
static constexpr size_t WS_NEEDED = OFF_ZP + 64;                       // ~155 MB

// ---------------- helpers ----------------
DEVINL void gload16(const bf16_t* g, bf16_t* l) {
  // async global->LDS, 16B per lane; LDS dest = wave-uniform base + lane*16, global addr per-lane
  __builtin_amdgcn_global_load_lds((const __attribute__((address_space(1))) void*)g,
                                   (__attribute__((address_space(3))) void*)l, 16, 0, 0);
}

// ---------------- K0a: transpose x (f32 [512][N]) -> xT_hi/xT_lo (bf16 [N][512]) ----------------
__global__ __launch_bounds__(256)
void xpose_kernel(const float* __restrict__ x, bf16_t* __restrict__ xTh, bf16_t* __restrict__ xTl) {
  __shared__ float t[32][33];
  const int n0 = blockIdx.x * 32, c0 = blockIdx.y * 32;
  const int tx = threadIdx.x & 31, ty = threadIdx.x >> 5;  // ty 0..7
#pragma unroll
  for (int r = 0; r < 4; ++r)
    t[ty + r * 8][tx] = x[(size_t)(c0 + ty + r * 8) * N_PIX + n0 + tx];  // t[c][n]
  __syncthreads();
  // write: 256 threads -> 256 bf16x8 chunks (32 n-rows x 4 col-groups x 2 planes)
  const int nl = threadIdx.x >> 3, sub = threadIdx.x & 7;
  const int c8 = (sub & 3) * 8, plane = sub >> 2;
  bf16x8 o;
#pragma unroll
  for (int k = 0; k < 8; ++k) {
    const float v = t[c8 + k][nl];
    if (plane == 0) {
      o[k] = (bf16_t)v;
    } else {
      const bf16_t hi = (bf16_t)v;
      o[k] = (bf16_t)(v - (float)hi);
    }
  }
  bf16_t* dst = plane ? xTl : xTh;
  *(bf16x8*)&dst[(size_t)(n0 + nl) * 512 + c0 + c8] = o;
}

// ---------------- K0b: build wqA [hi|lo|hi], wkv, scaled wpb, bna, zero page ----------------
static constexpr int PREP_W1 = 512 * 1536;           // wqA
static constexpr int PREP_W2 = 1024 * 512;           // wkv
static constexpr int PREP_W3 = 512 * 1024;           // wpb
static constexpr int PREP_TOT = PREP_W1 + PREP_W2 + PREP_W3 + 512 + 16;
__global__ __launch_bounds__(256)
void prep_kernel(const float* __restrict__ wq, const float* __restrict__ wp,
                 const float* __restrict__ gam, const float* __restrict__ bet,
                 const float* __restrict__ mu, const float* __restrict__ va,
                 bf16_t* __restrict__ wqA, bf16_t* __restrict__ wkv, bf16_t* __restrict__ wpb,
                 float* __restrict__ bna, float* __restrict__ zp) {
  const int i = blockIdx.x * 256 + threadIdx.x;
  if (i < PREP_W1) {
    const int r = i / 1536, c = i - r * 1536;
    const int o = (r >> 3) * 24 + (r & 7);  // q row in original w_qkv
    bf16_t out;
    if (c < 512) {
      out = (bf16_t)wq[o * 512 + c];
    } else if (c < 1024) {
      const float v = wq[o * 512 + c - 512];
      const bf16_t hi = (bf16_t)v;
      out = (bf16_t)(v - (float)hi);
    } else {
      out = (bf16_t)wq[o * 512 + c - 1024];
    }
    wqA[i] = out;
  } else if (i < PREP_W1 + PREP_W2) {
    const int j = i - PREP_W1;
    const int r = j >> 9, c = j & 511;
    const int h = (r & 511) >> 3;
    const int jj = (r < 512 ? 8 : 16) + (r & 7);
    wkv[j] = (bf16_t)wq[(h * 24 + jj) * 512 + c];
  } else if (i < PREP_W1 + PREP_W2 + PREP_W3) {
    const int j = i - PREP_W1 - PREP_W2;
    const int m = j >> 10;
    const float inv = gam[m] / sqrtf(va[m] + 1e-5f);
    wpb[j] = (bf16_t)(wp[j] * inv);
  } else if (i < PREP_W1 + PREP_W2 + PREP_W3 + 512) {
    const int k = i - PREP_W1 - PREP_W2 - PREP_W3;
    const float inv = gam[k] / sqrtf(va[k] + 1e-5f);
    bna[k] = bet[k] - mu[k] * inv;
  } else if (i < PREP_TOT) {
    zp[i - (PREP_W1 + PREP_W2 + PREP_W3 + 512)] = 0.f;
  }
}

// ---------------- K1: merged q/kv GEMM, 128x128 tile, BK=64, XOR-swizzled LDS ----------------
__global__ __launch_bounds__(256, 4)
void gemm_qkv_kernel(const bf16_t* __restrict__ wqA, const bf16_t* __restrict__ wkv,
                     const bf16_t* __restrict__ xTh, const bf16_t* __restrict__ xTl,
                     bf16_t* __restrict__ Qb, bf16_t* __restrict__ Qr, bf16_t* __restrict__ KV) {
  __shared__ __align__(16) bf16_t As[128 * 64];
  __shared__ __align__(16) bf16_t Bs[128 * 64];
  const int tid = threadIdx.x, wid = tid >> 6, lane = tid & 63;
  const int fr = lane & 15, fg = lane >> 4;
  const int wm = (wid >> 1) * 64, wn = (wid & 1) * 64;
  const int by = blockIdx.y;
  const bool isQ = by < 4;
  const int m0 = (isQ ? by : by - 4) * 128;
  const int n0 = blockIdx.x * 128;
  const int KA = isQ ? 1536 : 512;
  const bf16_t* Aptr = isQ ? wqA + (size_t)m0 * 1536 : wkv + (size_t)m0 * 512;
  const int srow = tid >> 3;                              // 0..31 (LDS row mod 32)
  const int soff = (((tid & 7) ^ (srow & 7)) * 8);        // pre-swizzled global chunk

  f32x4 acc[4][4] = {};

  for (int kk = 0; kk < KA; kk += 64) {
    const bf16_t* Bpl;
    int bcol;
    if (isQ) {
      Bpl  = (kk < 1024) ? xTh : xTl;
      bcol = (kk < 1024) ? (kk & 511) : (kk - 1024);
    } else {
      Bpl = xTh; bcol = kk;
    }
    __syncthreads();  // prev iter's LDS reads done
#pragma unroll
    for (int r = 0; r < 4; ++r) {
      gload16(Aptr + (size_t)(srow + 32 * r) * KA + kk + soff, As + (wid * 8 + 32 * r) * 64);
      gload16(Bpl + (size_t)(n0 + srow + 32 * r) * 512 + bcol + soff, Bs + (wid * 8 + 32 * r) * 64);
    }
    __syncthreads();  // drains vmcnt(0)
#pragma unroll
    for (int ks = 0; ks < 2; ++ks) {
      bf16x8 af[4], bfr[4];
#pragma unroll
      for (int i = 0; i < 4; ++i)
        af[i]  = *(const bf16x8*)&As[(wm + i * 16 + fr) * 64 + (((ks * 4 + fg) ^ (fr & 7)) * 8)];
#pragma unroll
      for (int j = 0; j < 4; ++j)
        bfr[j] = *(const bf16x8*)&Bs[(wn + j * 16 + fr) * 64 + (((ks * 4 + fg) ^ (fr & 7)) * 8)];
#pragma unroll
      for (int i = 0; i < 4; ++i)
#pragma unroll
        for (int j = 0; j < 4; ++j)
          acc[i][j] = __builtin_amdgcn_mfma_f32_16x16x32_bf16(af[i], bfr[j], acc[i][j], 0, 0, 0);
    }
  }

#pragma unroll
  for (int i = 0; i < 4; ++i)
#pragma unroll
    for (int r = 0; r < 4; ++r) {
      const int m = m0 + wm + i * 16 + fg * 4 + r;
#pragma unroll
      for (int j = 0; j < 4; ++j) {
        const int n = n0 + wn + j * 16 + fr;
        const float v = acc[i][j][r];
        if (isQ) {
          Qb[(size_t)m * N_PIX + n] = (bf16_t)v;                 // pre-relu (dwpw)
          Qr[(size_t)m * N_PIX + n] = (bf16_t)fmaxf(0.f, v);     // relu'd in f32 (attn) - sign exact
        } else {
          KV[(size_t)m * N_PIX + n] = (bf16_t)v;
        }
      }
    }
}

// ---------------- K5: proj GEMM (BN folded into A; epilogue +bna), BK=64, swizzled ----------------
__global__ __launch_bounds__(256, 4)
void gemm_proj_kernel(const bf16_t* __restrict__ A, const bf16_t* __restrict__ B,
                      float* __restrict__ Cout, const float* __restrict__ bna) {
  __shared__ __align__(16) bf16_t As[128 * 64];
  __shared__ __align__(16) bf16_t Bs[128 * 64];
  const int tid = threadIdx.x, wid = tid >> 6, lane = tid & 63;
  const int fr = lane & 15, fg = lane >> 4;
  const int wm = (wid >> 1) * 64, wn = (wid & 1) * 64;
  const int m0 = blockIdx.y * 128, n0 = blockIdx.x * 128;
  const int srow = tid >> 3;
  const int soff = (((tid & 7) ^ (srow & 7)) * 8);
  const bf16_t* Ab = A + (size_t)m0 * 1024;
  const bf16_t* Bb = B + (size_t)n0 * 1024;

  f32x4 acc[4][4] = {};

  for (int kk = 0; kk < 1024; kk += 64) {
    __syncthreads();
#pragma unroll
    for (int r = 0; r < 4; ++r) {
      gload16(Ab + (size_t)(srow + 32 * r) * 1024 + kk + soff, As + (wid * 8 + 32 * r) * 64);
      gload16(Bb + (size_t)(srow + 32 * r) * 1024 + kk + soff, Bs + (wid * 8 + 32 * r) * 64);
    }
    __syncthreads();
#pragma unroll
    for (int ks = 0; ks < 2; ++ks) {
      bf16x8 af[4], bfr[4];
#pragma unroll
      for (int i = 0; i < 4; ++i)
        af[i]  = *(const bf16x8*)&As[(wm + i * 16 + fr) * 64 + (((ks * 4 + fg) ^ (fr & 7)) * 8)];
#pragma unroll
      for (int j = 0; j < 4; ++j)
        bfr[j] = *(const bf16x8*)&Bs[(wn + j * 16 + fr) * 64 + (((ks * 4 + fg) ^ (fr & 7)) * 8)];
#pragma unroll
      for (int i = 0; i < 4; ++i)
#pragma unroll
        for (int j = 0; j < 4; ++j)
          acc[i][j] = __builtin_amdgcn_mfma_f32_16x16x32_bf16(af[i], bfr[j], acc[i][j], 0, 0, 0);
    }
  }

#pragma unroll
  for (int i = 0; i < 4; ++i)
#pragma unroll
    for (int r = 0; r < 4; ++r) {
      const int m = m0 + wm + i * 16 + fg * 4 + r;
      const float sh = bna[m];
#pragma unroll
      for (int j = 0; j < 4; ++j)
        Cout[(size_t)m * N_PIX + n0 + wn + j * 16 + fr] = acc[i][j][r] + sh;
    }
}

// ---------------- K2: fused dw 5x5 (pad 2) + grouped 1x1; all-bf16, DMA-staged (round-6 form) ----------------
// group g (0..191): typ=g%3 (0:q from Qb, 1:k, 2:v from KV), head=g/3; tile 16x64 pixels
__global__ __launch_bounds__(256)
void dwpw_kernel(const bf16_t* __restrict__ Qb, const bf16_t* __restrict__ KV,
                 const float* __restrict__ wdw, const float* __restrict__ wpw,
                 const bf16_t* __restrict__ zp, bf16_t* __restrict__ y) {
  const int g = blockIdx.y, t = blockIdx.x;
  const int typ = g % 3, head = g / 3;
  const int ty0 = (t >> 1) * 16, tx0 = (t & 1) * 64;
  const int tid = threadIdx.x, wid = tid >> 6, lane = tid & 63;
  __shared__ __align__(16) bf16_t sin_[8][20][80];  // rows: gy=ty0+row-2; cols: gx=tx0+c-8
  __shared__ float swd[8][25];
  __shared__ float swp[8][8];
  if (tid < 200) swd[tid / 25][tid % 25] = wdw[(g * 8 + tid / 25) * 25 + tid % 25];
  if (tid < 64)  swp[tid >> 3][tid & 7] = wpw[(g * 8 + (tid >> 3)) * 8 + (tid & 7)];
  const bf16_t* plane = (typ == 0) ? (Qb + (size_t)head * 8 * N_PIX)
                                   : (KV + (size_t)((typ == 2 ? 512 : 0) + head * 8) * N_PIX);
  bf16_t* sflat = &sin_[0][0][0];
  // 1600 16B chunks: chunk id -> [ch][row][c6*8..+7]; OOB lanes read the zero page
  for (int base = wid * 64; base < 1600; base += 256) {
    const int id  = base + lane;
    const int ch  = id / 200;
    const int rem = id - ch * 200;
    const int row = rem / 10;
    const int c6  = rem - row * 10;
    const int gy  = ty0 + row - 2;
    const int gx  = tx0 + c6 * 8 - 8;
    const bool ok = ((unsigned)gy < 128u) && ((unsigned)gx < 128u);
    const bf16_t* src = ok ? (plane + (size_t)ch * N_PIX + gy * 128 + gx) : zp;
    gload16(src, sflat + (size_t)base * 8);
  }
  __syncthreads();  // drains DMA (vmcnt 0) + weight loads

  const int px4 = (tid & 15) * 4, py = tid >> 4;  // 4 horizontal pixels per thread, 16 rows
  float dwres[8][4];
#pragma unroll
  for (int ch = 0; ch < 8; ++ch) {
    float o0 = 0.f, o1 = 0.f, o2 = 0.f, o3 = 0.f;
#pragma unroll
    for (int di = 0; di < 5; ++di) {
      bf16x4 a0 = *(const bf16x4*)&sin_[ch][py + di][px4 + 4];
      bf16x4 a1 = *(const bf16x4*)&sin_[ch][py + di][px4 + 8];
      bf16x4 a2 = *(const bf16x4*)&sin_[ch][py + di][px4 + 12];
      float vv[12] = {(float)a0[0], (float)a0[1], (float)a0[2], (float)a0[3],
                      (float)a1[0], (float)a1[1], (float)a1[2], (float)a1[3],
                      (float)a2[0], (float)a2[1], (float)a2[2], (float)a2[3]};
#pragma unroll
      for (int dj = 0; dj < 5; ++dj) {
        const float w = swd[ch][di * 5 + dj];
        o0 += vv[dj + 2] * w; o1 += vv[dj + 3] * w;
        o2 += vv[dj + 4] * w; o3 += vv[dj + 5] * w;
      }
    }
    dwres[ch][0] = o0; dwres[ch][1] = o1; dwres[ch][2] = o2; dwres[ch][3] = o3;
  }
#pragma unroll
  for (int oc = 0; oc < 8; ++oc) {
    float o[4] = {0.f, 0.f, 0.f, 0.f};
#pragma unroll
    for (int ic = 0; ic < 8; ++ic) {
      const float w = swp[oc][ic];
#pragma unroll
      for (int u = 0; u < 4; ++u) o[u] += dwres[ic][u] * w;
    }
    bf16x4 ov;
#pragma unroll
    for (int u = 0; u < 4; ++u) ov[u] = (bf16_t)o[u];
    *(bf16x4*)&y[(size_t)(8 * g + oc) * N_PIX + (ty0 + py) * 128 + tx0 + px4] = ov;
  }
}

// ---------------- K3a: per-slice partial vk[d][e] = sum_n v_d * relu(k_e) (+ k-sum row) ----------------
__global__ __launch_bounds__(256)
void vk_partial_kernel(const bf16_t* __restrict__ KV, const bf16_t* __restrict__ yb,
                       float* __restrict__ part) {
  const int h = blockIdx.y, s = blockIdx.x;  // s: 0..7 pixel slices
  const bf16_t *kb, *vb;
  if (h < 64) {
    kb = KV + (size_t)(h * 8) * N_PIX;
    vb = KV + (size_t)(512 + h * 8) * N_PIX;
  } else {
    kb = yb + (size_t)(24 * (h - 64) + 8) * N_PIX;
    vb = yb + (size_t)(24 * (h - 64) + 16) * N_PIX;
  }
  float a[8][8] = {};
  float ak[8] = {};
  const int p0 = s * 2048 + (int)threadIdx.x * 8;   // 8 px per thread, single pass
  float kq[8][8], vq[8][8];
#pragma unroll
  for (int e = 0; e < 8; ++e) {
    bf16x8 kk = *(const bf16x8*)&kb[(size_t)e * N_PIX + p0];
#pragma unroll
    for (int u = 0; u < 8; ++u) kq[e][u] = fmaxf(0.f, (float)kk[u]);
  }
#pragma unroll
  for (int d = 0; d < 8; ++d) {
    bf16x8 vv = *(const bf16x8*)&vb[(size_t)d * N_PIX + p0];
#pragma unroll
    for (int u = 0; u < 8; ++u) vq[d][u] = (float)vv[u];
  }
#pragma unroll
  for (int d = 0; d < 8; ++d)
#pragma unroll
    for (int e = 0; e < 8; ++e)
#pragma unroll
      for (int u = 0; u < 8; ++u) a[d][e] += vq[d][u] * kq[e][u];
#pragma unroll
  for (int e = 0; e < 8; ++e)
#pragma unroll
    for (int u = 0; u < 8; ++u) ak[e] += kq[e][u];

  __shared__ float red[4][72];
  const int lane = threadIdx.x & 63, wid = threadIdx.x >> 6;
#pragma unroll
  for (int i = 0; i < 72; ++i) {
    float v = (i < 64) ? a[i >> 3][i & 7] : ak[i - 64];
    v += __shfl_xor(v, 32); v += __shfl_xor(v, 16); v += __shfl_xor(v, 8);
    v += __shfl_xor(v, 4);  v += __shfl_xor(v, 2);  v += __shfl_xor(v, 1);
    if (lane == 0) red[wid][i] = v;
  }
  __syncthreads();
  if (threadIdx.x < 72) {
    const float sum_ = red[0][threadIdx.x] + red[1][threadIdx.x] + red[2][threadIdx.x] + red[3][threadIdx.x];
    part[((size_t)h * 8 + s) * 72 + threadIdx.x] = sum_;
  }
}

// ---------------- K3b: deterministic reduce of 8 slices ----------------
__global__ __launch_bounds__(128)
void vk_reduce_kernel(const float* __restrict__ part, float* __restrict__ vk) {
  const int h = blockIdx.x;  // 0..127
  const int i = threadIdx.x;
  if (i < 72) {
    float s = 0.f;
#pragma unroll
    for (int t = 0; t < 8; ++t) s += part[((size_t)h * 8 + t) * 72 + i];
    vk[(size_t)h * 72 + i] = s;
  }
}

// ---------------- K4: attention apply -> attT bf16 [N][1024] ----------------
__global__ __launch_bounds__(256)
void attn_kernel(const bf16_t* __restrict__ Qr, const bf16_t* __restrict__ yb,
                 const float* __restrict__ vk, bf16_t* __restrict__ attT) {
  const int n0 = blockIdx.x * 32;
  const int tid = threadIdx.x;
  const int px = tid & 31, hl = tid >> 5;  // hl: 0..7
  __shared__ __align__(16) bf16_t att_s[32 * 512];
  __shared__ float vk_s[576];
  for (int grp = 0; grp < 2; ++grp) {
    for (int hg = 0; hg < 8; ++hg) {
      __syncthreads();  // protect vk_s (and att_s on grp switch)
      for (int i = tid; i < 576; i += 256)
        vk_s[i] = vk[((size_t)grp * 64 + hg * 8) * 72 + i];
      __syncthreads();
      const int hh = hg * 8 + hl;  // head within half (0..63)
      float q[8];
      if (grp == 0) {
        const bf16_t* plane = Qr + (size_t)(hh * 8) * N_PIX + n0 + px;
#pragma unroll
        for (int e = 0; e < 8; ++e) q[e] = (float)plane[(size_t)e * N_PIX];  // already relu'd
      } else {
        const bf16_t* plane = yb + (size_t)(24 * hh) * N_PIX + n0 + px;
#pragma unroll
        for (int e = 0; e < 8; ++e) q[e] = fmaxf(0.f, (float)plane[(size_t)e * N_PIX]);
      }
      float den = 1e-15f;
#pragma unroll
      for (int e = 0; e < 8; ++e) den += vk_s[hl * 72 + 64 + e] * q[e];
      const float rden = 1.0f / den;
      bf16x8 r8;
#pragma unroll
      for (int d = 0; d < 8; ++d) {
        float num = 0.f;
#pragma unroll
        for (int e = 0; e < 8; ++e) num += vk_s[hl * 72 + d * 8 + e] * q[e];
        r8[d] = (bf16_t)(num * rden);
      }
      const int chunk = hg * 8 + hl;  // 16B chunk index within half-row
      *(bf16x8*)&att_s[px * 512 + ((chunk ^ (px & 7)) << 3)] = r8;
    }
    __syncthreads();
    bf16_t* dst = attT + (size_t)n0 * 1024 + grp * 512;
    for (int i = tid; i < 2048; i += 256) {
      const int r = i >> 6, cc = i & 63;
      bf16x8 v = *(const bf16x8*)&att_s[r * 512 + (((cc ^ (r & 7))) << 3)];
      *(bf16x8*)&dst[(size_t)r * 1024 + cc * 8] = v;
    }
  }
}

// ---------------- launch ----------------
extern "C" void kernel_launch(void* const* d_in, const int* in_sizes, int n_in,
                              void* d_out, int out_size, void* d_ws, size_t ws_size,
                              hipStream_t stream) {
  if (ws_size < WS_NEEDED) return;  // need ~155 MB scratch
  const float* x      = (const float*)d_in[0];
  const float* w_qkv  = (const float*)d_in[1];
  const float* w_dw   = (const float*)d_in[2];
  const float* w_pw   = (const float*)d_in[3];
  const float* w_proj = (const float*)d_in[4];
  const float* gam    = (const float*)d_in[5];
  const float* bet    = (const float*)d_in[6];
  const float* mu     = (const float*)d_in[7];
  const float* va     = (const float*)d_in[8];

  char* w = (char*)d_ws;
  bf16_t* Qb   = (bf16_t*)(w + OFF_QB);
  bf16_t* Qr   = (bf16_t*)(w + OFF_QR);
  bf16_t* KV   = (bf16_t*)(w + OFF_KV);
  bf16_t* yb   = (bf16_t*)(w + OFF_Y);
  bf16_t* xTh  = (bf16_t*)(w + OFF_XTH);  // aliased with attT (dead after K1)
  bf16_t* xTl  = (bf16_t*)(w + OFF_XTL);
  bf16_t* attT = (bf16_t*)(w + OFF_ATT);
  bf16_t* wqA  = (bf16_t*)(w + OFF_WQA);
  bf16_t* wkv  = (bf16_t*)(w + OFF_WKV);
  bf16_t* wpb  = (bf16_t*)(w + OFF_WP);
  float*  vk   = (float*)(w + OFF_VK);
  float*  part = (float*)(w + OFF_VKP);
  float*  bna  = (float*)(w + OFF_BNA);
  float*  zp   = (float*)(w + OFF_ZP);

  dim3 blk(256);
  // weights + BN fold + zero page (once)
  prep_kernel<<<dim3((PREP_TOT + 255) / 256), blk, 0, stream>>>(
      w_qkv, w_proj, gam, bet, mu, va, wqA, wkv, wpb, bna, zp);

  for (int b = 0; b < 2; ++b) {
    const float* xb = x + (size_t)b * 512 * N_PIX;
    float* outb = (float*)d_out + (size_t)b * 512 * N_PIX;
    // K0a: x -> xT hi/lo bf16
    xpose_kernel<<<dim3(512, 16), blk, 0, stream>>>(xb, xTh, xTl);
    // K1: merged q (3-term via K=1536) + kv GEMM
    gemm_qkv_kernel<<<dim3(128, 12), blk, 0, stream>>>(wqA, wkv, xTh, xTl, Qb, Qr, KV);
    // K2: fused dw 5x5 + grouped pw -> y (interleaved bf16)
    dwpw_kernel<<<dim3(16, 192), blk, 0, stream>>>(Qb, KV, w_dw, w_pw, (const bf16_t*)zp, yb);
    // K3: vk accumulation (partials, then deterministic reduce)
    vk_partial_kernel<<<dim3(8, 128), blk, 0, stream>>>(KV, yb, part);
    vk_reduce_kernel<<<dim3(128), dim3(128), 0, stream>>>(part, vk);
    // K4: attention apply -> attT
    attn_kernel<<<dim3(512), blk, 0, stream>>>(Qr, yb, vk, attT);
    // K5: out = wpb * att + bna (M=512, K=1024), f32 out
    gemm_proj_kernel<<<dim3(128, 4), blk, 0, stream>>>(wpb, attT, outb, bna);
  }
}

// Round 9
// 350.169 us; speedup vs baseline: 1.2170x; 1.0539x over previous
//
#include <hip/hip_runtime.h>

typedef __bf16 bf16_t;
typedef __bf16 bf16x8 __attribute__((ext_vector_type(8)));
typedef __bf16 bf16x4 __attribute__((ext_vector_type(4)));
typedef float  f32x4  __attribute__((ext_vector_type(4)));
typedef _Float16 h16;
typedef _Float16 h16x2 __attribute__((ext_vector_type(2)));
typedef _Float16 h16x4 __attribute__((ext_vector_type(4)));
typedef _Float16 h16x8 __attribute__((ext_vector_type(8)));

#define DEVINL __device__ __forceinline__

static constexpr size_t N_PIX = 16384;

// ---------------- per-batch workspace layout (bytes) ----------------
static constexpr size_t OFF_QB  = 0;                                   // Qb f16 [512][N] (pre-relu, dwpw input)
static constexpr size_t SZ_QB   = (size_t)512 * N_PIX * 2;             // 16.78 MB
static constexpr size_t OFF_QR  = OFF_QB + SZ_QB;                      // Qr f16 [512][N] (relu'd, qn input)
static constexpr size_t SZ_QR   = SZ_QB;
static constexpr size_t OFF_KV  = OFF_QR + SZ_QR;                      // KV f16 [1024][N]: rows 0..511 K, 512..1023 V
static constexpr size_t SZ_KV   = (size_t)1024 * N_PIX * 2;            // 33.55 MB
static constexpr size_t OFF_Y   = OFF_KV + SZ_KV;                      // y f16 [1536][N] (interleaved 24/head)
static constexpr size_t SZ_Y    = (size_t)1536 * N_PIX * 2;            // 50.33 MB
static constexpr size_t OFF_ATT = OFF_Y + SZ_Y;                        // qnT bf16 [N][1024]; xTh/xTl aliased
static constexpr size_t SZ_ATT  = (size_t)N_PIX * 1024 * 2;            // 33.55 MB
static constexpr size_t OFF_XTH = OFF_ATT;                             // xT_hi bf16 [N][512] (dead after qkv GEMM)
static constexpr size_t OFF_XTL = OFF_ATT + (size_t)N_PIX * 512 * 2;   // xT_lo bf16 [N][512]
static constexpr size_t OFF_WQA = OFF_ATT + SZ_ATT;                    // wqA bf16 [512][1536] = [hi|lo|hi]
static constexpr size_t SZ_WQA  = (size_t)512 * 1536 * 2;
static constexpr size_t OFF_WKV = OFF_WQA + SZ_WQA;                    // wkv bf16 [1024][512]
static constexpr size_t SZ_WKV  = (size_t)1024 * 512 * 2;
static constexpr size_t OFF_WP  = OFF_WKV + SZ_WKV;                    // wpb bf16 [512][1024], pre-scaled by bn inv
static constexpr size_t SZ_WP   = (size_t)512 * 1024 * 2;
static constexpr size_t OFF_VK  = OFF_WP + SZ_WP;                      // vk f32 [128][72]
static constexpr size_t SZ_VK   = (size_t)128 * 72 * 4;
static constexpr size_t OFF_VKP = OFF_VK + SZ_VK;                      // vk partials f32 [128][8][72]
static constexpr size_t SZ_VKP  = (size_t)128 * 8 * 72 * 4;
static constexpr size_t OFF_BNA = OFF_VKP + SZ_VKP;                    // f32[512]
static constexpr size_t OFF_ZP  = OFF_BNA + 2048;                      // 64B zero page
static constexpr size_t OFF_W2  = OFF_ZP + 64;                         // W2 bf16 [512][1024] (wpb x blockdiag(vk))
static constexpr size_t SZ_W2   = (size_t)512 * 1024 * 2;
static constexpr size_t WS_NEEDED = OFF_W2 + SZ_W2;                    // ~156 MB

// ---------------- helpers ----------------
DEVINL void gload16(const void* g, void* l) {
  // async global->LDS, 16B per lane; LDS dest = wave-uniform base + lane*16, global addr per-lane
  __builtin_amdgcn_global_load_lds((const __attribute__((address_space(1))) void*)g,
                                   (__attribute__((address_space(3))) void*)l, 16, 0, 0);
}

// ---------------- K0a: transpose x (f32 [512][N]) -> xT_hi/xT_lo (bf16 [N][512]) ----------------
__global__ __launch_bounds__(256)
void xpose_kernel(const float* __restrict__ x, bf16_t* __restrict__ xTh, bf16_t* __restrict__ xTl) {
  __shared__ float t[32][33];
  const int n0 = blockIdx.x * 32, c0 = blockIdx.y * 32;
  const int tx = threadIdx.x & 31, ty = threadIdx.x >> 5;  // ty 0..7
#pragma unroll
  for (int r = 0; r < 4; ++r)
    t[ty + r * 8][tx] = x[(size_t)(c0 + ty + r * 8) * N_PIX + n0 + tx];  // t[c][n]
  __syncthreads();
  const int nl = threadIdx.x >> 3, sub = threadIdx.x & 7;
  const int c8 = (sub & 3) * 8, plane = sub >> 2;
  bf16x8 o;
#pragma unroll
  for (int k = 0; k < 8; ++k) {
    const float v = t[c8 + k][nl];
    if (plane == 0) {
      o[k] = (bf16_t)v;
    } else {
      const bf16_t hi = (bf16_t)v;
      o[k] = (bf16_t)(v - (float)hi);
    }
  }
  bf16_t* dst = plane ? xTl : xTh;
  *(bf16x8*)&dst[(size_t)(n0 + nl) * 512 + c0 + c8] = o;
}

// ---------------- K0b: build wqA [hi|lo|hi], wkv, scaled wpb, bna, zero page ----------------
static constexpr int PREP_W1 = 512 * 1536;           // wqA
static constexpr int PREP_W2 = 1024 * 512;           // wkv
static constexpr int PREP_W3 = 512 * 1024;           // wpb
static constexpr int PREP_TOT = PREP_W1 + PREP_W2 + PREP_W3 + 512 + 16;
__global__ __launch_bounds__(256)
void prep_kernel(const float* __restrict__ wq, const float* __restrict__ wp,
                 const float* __restrict__ gam, const float* __restrict__ bet,
                 const float* __restrict__ mu, const float* __restrict__ va,
                 bf16_t* __restrict__ wqA, bf16_t* __restrict__ wkv, bf16_t* __restrict__ wpb,
                 float* __restrict__ bna, float* __restrict__ zp) {
  const int i = blockIdx.x * 256 + threadIdx.x;
  if (i < PREP_W1) {
    const int r = i / 1536, c = i - r * 1536;
    const int o = (r >> 3) * 24 + (r & 7);  // q row in original w_qkv
    bf16_t out;
    if (c < 512) {
      out = (bf16_t)wq[o * 512 + c];
    } else if (c < 1024) {
      const float v = wq[o * 512 + c - 512];
      const bf16_t hi = (bf16_t)v;
      out = (bf16_t)(v - (float)hi);
    } else {
      out = (bf16_t)wq[o * 512 + c - 1024];
    }
    wqA[i] = out;
  } else if (i < PREP_W1 + PREP_W2) {
    const int j = i - PREP_W1;
    const int r = j >> 9, c = j & 511;
    const int h = (r & 511) >> 3;
    const int jj = (r < 512 ? 8 : 16) + (r & 7);
    wkv[j] = (bf16_t)wq[(h * 24 + jj) * 512 + c];
  } else if (i < PREP_W1 + PREP_W2 + PREP_W3) {
    const int j = i - PREP_W1 - PREP_W2;
    const int m = j >> 10;
    const float inv = gam[m] / sqrtf(va[m] + 1e-5f);
    wpb[j] = (bf16_t)(wp[j] * inv);
  } else if (i < PREP_W1 + PREP_W2 + PREP_W3 + 512) {
    const int k = i - PREP_W1 - PREP_W2 - PREP_W3;
    const float inv = gam[k] / sqrtf(va[k] + 1e-5f);
    bna[k] = bet[k] - mu[k] * inv;
  } else if (i < PREP_TOT) {
    zp[i - (PREP_W1 + PREP_W2 + PREP_W3 + 512)] = 0.f;
  }
}

// ---------------- K1: merged q/kv GEMM, 128x128 tile, BK=64, XOR-swizzled LDS ----------------
__global__ __launch_bounds__(256, 4)
void gemm_qkv_kernel(const bf16_t* __restrict__ wqA, const bf16_t* __restrict__ wkv,
                     const bf16_t* __restrict__ xTh, const bf16_t* __restrict__ xTl,
                     h16* __restrict__ Qb, h16* __restrict__ Qr, h16* __restrict__ KV) {
  __shared__ __align__(16) bf16_t As[128 * 64];
  __shared__ __align__(16) bf16_t Bs[128 * 64];
  const int tid = threadIdx.x, wid = tid >> 6, lane = tid & 63;
  const int fr = lane & 15, fg = lane >> 4;
  const int wm = (wid >> 1) * 64, wn = (wid & 1) * 64;
  const int by = blockIdx.y;
  const bool isQ = by < 4;
  const int m0 = (isQ ? by : by - 4) * 128;
  const int n0 = blockIdx.x * 128;
  const int KA = isQ ? 1536 : 512;
  const bf16_t* Aptr = isQ ? wqA + (size_t)m0 * 1536 : wkv + (size_t)m0 * 512;
  const int srow = tid >> 3;                              // 0..31 (LDS row mod 32)
  const int soff = (((tid & 7) ^ (srow & 7)) * 8);        // pre-swizzled global chunk

  f32x4 acc[4][4] = {};

  for (int kk = 0; kk < KA; kk += 64) {
    const bf16_t* Bpl;
    int bcol;
    if (isQ) {
      Bpl  = (kk < 1024) ? xTh : xTl;
      bcol = (kk < 1024) ? (kk & 511) : (kk - 1024);
    } else {
      Bpl = xTh; bcol = kk;
    }
    __syncthreads();  // prev iter's LDS reads done
#pragma unroll
    for (int r = 0; r < 4; ++r) {
      gload16(Aptr + (size_t)(srow + 32 * r) * KA + kk + soff, As + (wid * 8 + 32 * r) * 64);
      gload16(Bpl + (size_t)(n0 + srow + 32 * r) * 512 + bcol + soff, Bs + (wid * 8 + 32 * r) * 64);
    }
    __syncthreads();  // drains vmcnt(0)
#pragma unroll
    for (int ks = 0; ks < 2; ++ks) {
      bf16x8 af[4], bfr[4];
#pragma unroll
      for (int i = 0; i < 4; ++i)
        af[i]  = *(const bf16x8*)&As[(wm + i * 16 + fr) * 64 + (((ks * 4 + fg) ^ (fr & 7)) * 8)];
#pragma unroll
      for (int j = 0; j < 4; ++j)
        bfr[j] = *(const bf16x8*)&Bs[(wn + j * 16 + fr) * 64 + (((ks * 4 + fg) ^ (fr & 7)) * 8)];
#pragma unroll
      for (int i = 0; i < 4; ++i)
#pragma unroll
        for (int j = 0; j < 4; ++j)
          acc[i][j] = __builtin_amdgcn_mfma_f32_16x16x32_bf16(af[i], bfr[j], acc[i][j], 0, 0, 0);
    }
  }

#pragma unroll
  for (int i = 0; i < 4; ++i)
#pragma unroll
    for (int r = 0; r < 4; ++r) {
      const int m = m0 + wm + i * 16 + fg * 4 + r;
#pragma unroll
      for (int j = 0; j < 4; ++j) {
        const int n = n0 + wn + j * 16 + fr;
        const float v = acc[i][j][r];
        if (isQ) {
          Qb[(size_t)m * N_PIX + n] = (h16)v;                 // pre-relu (dwpw)
          Qr[(size_t)m * N_PIX + n] = (h16)fmaxf(0.f, v);     // relu'd in f32 - sign exact
        } else {
          KV[(size_t)m * N_PIX + n] = (h16)v;
        }
      }
    }
}

// ---------------- K5: proj GEMM out = W2 x qnT + bna, BK=64, swizzled ----------------
__global__ __launch_bounds__(256, 4)
void gemm_proj_kernel(const bf16_t* __restrict__ A, const bf16_t* __restrict__ B,
                      float* __restrict__ Cout, const float* __restrict__ bna) {
  __shared__ __align__(16) bf16_t As[128 * 64];
  __shared__ __align__(16) bf16_t Bs[128 * 64];
  const int tid = threadIdx.x, wid = tid >> 6, lane = tid & 63;
  const int fr = lane & 15, fg = lane >> 4;
  const int wm = (wid >> 1) * 64, wn = (wid & 1) * 64;
  const int m0 = blockIdx.y * 128, n0 = blockIdx.x * 128;
  const int srow = tid >> 3;
  const int soff = (((tid & 7) ^ (srow & 7)) * 8);
  const bf16_t* Ab = A + (size_t)m0 * 1024;
  const bf16_t* Bb = B + (size_t)n0 * 1024;

  f32x4 acc[4][4] = {};

  for (int kk = 0; kk < 1024; kk += 64) {
    __syncthreads();
#pragma unroll
    for (int r = 0; r < 4; ++r) {
      gload16(Ab + (size_t)(srow + 32 * r) * 1024 + kk + soff, As + (wid * 8 + 32 * r) * 64);
      gload16(Bb + (size_t)(srow + 32 * r) * 1024 + kk + soff, Bs + (wid * 8 + 32 * r) * 64);
    }
    __syncthreads();
#pragma unroll
    for (int ks = 0; ks < 2; ++ks) {
      bf16x8 af[4], bfr[4];
#pragma unroll
      for (int i = 0; i < 4; ++i)
        af[i]  = *(const bf16x8*)&As[(wm + i * 16 + fr) * 64 + (((ks * 4 + fg) ^ (fr & 7)) * 8)];
#pragma unroll
      for (int j = 0; j < 4; ++j)
        bfr[j] = *(const bf16x8*)&Bs[(wn + j * 16 + fr) * 64 + (((ks * 4 + fg) ^ (fr & 7)) * 8)];
#pragma unroll
      for (int i = 0; i < 4; ++i)
#pragma unroll
        for (int j = 0; j < 4; ++j)
          acc[i][j] = __builtin_amdgcn_mfma_f32_16x16x32_bf16(af[i], bfr[j], acc[i][j], 0, 0, 0);
    }
  }

#pragma unroll
  for (int i = 0; i < 4; ++i)
#pragma unroll
    for (int r = 0; r < 4; ++r) {
      const int m = m0 + wm + i * 16 + fg * 4 + r;
      const float sh = bna[m];
#pragma unroll
      for (int j = 0; j < 4; ++j)
        Cout[(size_t)m * N_PIX + n0 + wn + j * 16 + fr] = acc[i][j][r] + sh;
    }
}

// ---------------- K2: fused dw 5x5 (pad 2) + grouped 1x1; f16 packed math, DMA-staged ----------------
// group g (0..191): typ=g%3 (0:q from Qb, 1:k, 2:v from KV), head=g/3; tile 16x64 pixels
__global__ __launch_bounds__(256)
void dwpw_kernel(const h16* __restrict__ Qb, const h16* __restrict__ KV,
                 const float* __restrict__ wdw, const float* __restrict__ wpw,
                 const h16* __restrict__ zp, h16* __restrict__ y) {
  const int g = blockIdx.y, t = blockIdx.x;
  const int typ = g % 3, head = g / 3;
  const int ty0 = (t >> 1) * 16, tx0 = (t & 1) * 64;
  const int tid = threadIdx.x, wid = tid >> 6, lane = tid & 63;
  __shared__ __align__(16) h16 sin_[8][20][80];  // rows: gy=ty0+row-2; cols: gx=tx0+c-8
  __shared__ h16x2 swd2[8][25];
  __shared__ h16x2 swp2[8][8];
  if (tid < 200) {
    const h16 w = (h16)wdw[(g * 8 + tid / 25) * 25 + tid % 25];
    h16x2 w2; w2[0] = w; w2[1] = w;
    swd2[tid / 25][tid % 25] = w2;
  }
  if (tid < 64) {
    const h16 w = (h16)wpw[(g * 8 + (tid >> 3)) * 8 + (tid & 7)];
    h16x2 w2; w2[0] = w; w2[1] = w;
    swp2[tid >> 3][tid & 7] = w2;
  }
  const h16* plane = (typ == 0) ? (Qb + (size_t)head * 8 * N_PIX)
                                : (KV + (size_t)((typ == 2 ? 512 : 0) + head * 8) * N_PIX);
  h16* sflat = &sin_[0][0][0];
  // 1600 16B chunks: chunk id -> [ch][row][c6*8..+7]; OOB lanes read the zero page
  for (int base = wid * 64; base < 1600; base += 256) {
    const int id  = base + lane;
    const int ch  = id / 200;
    const int rem = id - ch * 200;
    const int row = rem / 10;
    const int c6  = rem - row * 10;
    const int gy  = ty0 + row - 2;
    const int gx  = tx0 + c6 * 8 - 8;
    const bool ok = ((unsigned)gy < 128u) && ((unsigned)gx < 128u);
    const h16* src = ok ? (plane + (size_t)ch * N_PIX + gy * 128 + gx) : zp;
    gload16(src, sflat + (size_t)base * 8);
  }
  __syncthreads();  // drains DMA (vmcnt 0) + weight stores

  const int px4 = (tid & 15) * 4, py = tid >> 4;  // 4 horizontal px per thread, 16 rows
  h16x2 dwa[8][2];
#pragma unroll
  for (int ch = 0; ch < 8; ++ch) {
    h16x2 A0 = 0, A1 = 0;  // px pair (0,1), (2,3)
#pragma unroll
    for (int di = 0; di < 5; ++di) {
      const uint2 w0 = *(const uint2*)&sin_[ch][py + di][px4 + 4];
      const uint2 w1 = *(const uint2*)&sin_[ch][py + di][px4 + 8];
      const uint2 w2v = *(const uint2*)&sin_[ch][py + di][px4 + 12];
      const unsigned u1 = w0.y, u2 = w1.x, u3 = w1.y, u4 = w2v.x;
      // Pk = (h_k, h_{k+1}); h index relative to col px4+4
      const h16x2 P2 = __builtin_bit_cast(h16x2, u1);
      const h16x2 P3 = __builtin_bit_cast(h16x2, (u2 << 16) | (u1 >> 16));
      const h16x2 P4 = __builtin_bit_cast(h16x2, u2);
      const h16x2 P5 = __builtin_bit_cast(h16x2, (u3 << 16) | (u2 >> 16));
      const h16x2 P6 = __builtin_bit_cast(h16x2, u3);
      const h16x2 P7 = __builtin_bit_cast(h16x2, (u4 << 16) | (u3 >> 16));
      const h16x2 P8 = __builtin_bit_cast(h16x2, u4);
      h16x2 wd;
      wd = swd2[ch][di * 5 + 0]; A0 += wd * P2; A1 += wd * P4;
      wd = swd2[ch][di * 5 + 1]; A0 += wd * P3; A1 += wd * P5;
      wd = swd2[ch][di * 5 + 2]; A0 += wd * P4; A1 += wd * P6;
      wd = swd2[ch][di * 5 + 3]; A0 += wd * P5; A1 += wd * P7;
      wd = swd2[ch][di * 5 + 4]; A0 += wd * P6; A1 += wd * P8;
    }
    dwa[ch][0] = A0; dwa[ch][1] = A1;
  }
#pragma unroll
  for (int oc = 0; oc < 8; ++oc) {
    h16x2 o0 = 0, o1 = 0;
#pragma unroll
    for (int ic = 0; ic < 8; ++ic) {
      const h16x2 w = swp2[oc][ic];
      o0 += w * dwa[ic][0];
      o1 += w * dwa[ic][1];
    }
    h16x4 ov; ov[0] = o0[0]; ov[1] = o0[1]; ov[2] = o1[0]; ov[3] = o1[1];
    *(h16x4*)&y[(size_t)(8 * g + oc) * N_PIX + (ty0 + py) * 128 + tx0 + px4] = ov;
  }
}

// ---------------- K3a: per-slice partial vk[d][e] = sum_n v_d * relu(k_e) (+ k-sum row) ----------------
__global__ __launch_bounds__(256)
void vk_partial_kernel(const h16* __restrict__ KV, const h16* __restrict__ yb,
                       float* __restrict__ part) {
  const int h = blockIdx.y, s = blockIdx.x;  // s: 0..7 pixel slices
  const h16 *kb, *vb;
  if (h < 64) {
    kb = KV + (size_t)(h * 8) * N_PIX;
    vb = KV + (size_t)(512 + h * 8) * N_PIX;
  } else {
    kb = yb + (size_t)(24 * (h - 64) + 8) * N_PIX;
    vb = yb + (size_t)(24 * (h - 64) + 16) * N_PIX;
  }
  float a[8][8] = {};
  float ak[8] = {};
  const int p0 = s * 2048 + (int)threadIdx.x * 8;   // 8 px per thread, single pass
  float kq[8][8], vq[8][8];
#pragma unroll
  for (int e = 0; e < 8; ++e) {
    h16x8 kk = *(const h16x8*)&kb[(size_t)e * N_PIX + p0];
#pragma unroll
    for (int u = 0; u < 8; ++u) kq[e][u] = fmaxf(0.f, (float)kk[u]);
  }
#pragma unroll
  for (int d = 0; d < 8; ++d) {
    h16x8 vv = *(const h16x8*)&vb[(size_t)d * N_PIX + p0];
#pragma unroll
    for (int u = 0; u < 8; ++u) vq[d][u] = (float)vv[u];
  }
#pragma unroll
  for (int d = 0; d < 8; ++d)
#pragma unroll
    for (int e = 0; e < 8; ++e)
#pragma unroll
      for (int u = 0; u < 8; ++u) a[d][e] += vq[d][u] * kq[e][u];
#pragma unroll
  for (int e = 0; e < 8; ++e)
#pragma unroll
    for (int u = 0; u < 8; ++u) ak[e] += kq[e][u];

  __shared__ float red[4][72];
  const int lane = threadIdx.x & 63, wid = threadIdx.x >> 6;
#pragma unroll
  for (int i = 0; i < 72; ++i) {
    float v = (i < 64) ? a[i >> 3][i & 7] : ak[i - 64];
    v += __shfl_xor(v, 32); v += __shfl_xor(v, 16); v += __shfl_xor(v, 8);
    v += __shfl_xor(v, 4);  v += __shfl_xor(v, 2);  v += __shfl_xor(v, 1);
    if (lane == 0) red[wid][i] = v;
  }
  __syncthreads();
  if (threadIdx.x < 72) {
    const float sum_ = red[0][threadIdx.x] + red[1][threadIdx.x] + red[2][threadIdx.x] + red[3][threadIdx.x];
    part[((size_t)h * 8 + s) * 72 + threadIdx.x] = sum_;
  }
}

// ---------------- K3b: deterministic reduce of 8 slices ----------------
__global__ __launch_bounds__(128)
void vk_reduce_kernel(const float* __restrict__ part, float* __restrict__ vk) {
  const int h = blockIdx.x;  // 0..127
  const int i = threadIdx.x;
  if (i < 72) {
    float s = 0.f;
#pragma unroll
    for (int t = 0; t < 8; ++t) s += part[((size_t)h * 8 + t) * 72 + i];
    vk[(size_t)h * 72 + i] = s;
  }
}

// ---------------- K3c: W2[m][h*8+e] = sum_d wpb[m][h*8+d] * vk[h][d][e] ----------------
__global__ __launch_bounds__(256)
void w2_kernel(const bf16_t* __restrict__ wpb, const float* __restrict__ vkm,
               bf16_t* __restrict__ W2) {
  const int idx = blockIdx.x * 256 + threadIdx.x;  // 512*1024
  const int m = idx >> 10, c = idx & 1023;
  const int h = c >> 3, e = c & 7;
  float s = 0.f;
#pragma unroll
  for (int d = 0; d < 8; ++d)
    s += (float)wpb[(size_t)m * 1024 + h * 8 + d] * vkm[h * 72 + d * 8 + e];
  W2[idx] = (bf16_t)s;
}

// ---------------- K4: qn = relu(q) / den -> qnT bf16 [N][1024] ----------------
__global__ __launch_bounds__(256)
void qn_kernel(const h16* __restrict__ Qr, const h16* __restrict__ yb,
               const float* __restrict__ vk, bf16_t* __restrict__ qnT) {
  const int n0 = blockIdx.x * 32;
  const int tid = threadIdx.x;
  const int px = tid & 31, hl = tid >> 5;  // hl: 0..7
  __shared__ __align__(16) bf16_t att_s[32 * 512];
  __shared__ float ak_s[64];               // [8 heads][8] per pass
  for (int grp = 0; grp < 2; ++grp) {
    for (int hg = 0; hg < 8; ++hg) {
      __syncthreads();  // protect ak_s (and att_s on grp switch)
      if (tid < 64)
        ak_s[tid] = vk[((size_t)grp * 64 + hg * 8 + (tid >> 3)) * 72 + 64 + (tid & 7)];
      __syncthreads();
      const int hh = hg * 8 + hl;  // head within half (0..63)
      float q[8];
      if (grp == 0) {
        const h16* plane = Qr + (size_t)(hh * 8) * N_PIX + n0 + px;
#pragma unroll
        for (int e = 0; e < 8; ++e) q[e] = (float)plane[(size_t)e * N_PIX];  // already relu'd
      } else {
        const h16* plane = yb + (size_t)(24 * hh) * N_PIX + n0 + px;
#pragma unroll
        for (int e = 0; e < 8; ++e) q[e] = fmaxf(0.f, (float)plane[(size_t)e * N_PIX]);
      }
      float den = 1e-15f;
#pragma unroll
      for (int e = 0; e < 8; ++e) den += ak_s[hl * 8 + e] * q[e];
      const float rden = 1.0f / den;
      bf16x8 r8;
#pragma unroll
      for (int e = 0; e < 8; ++e) r8[e] = (bf16_t)(q[e] * rden);
      const int chunk = hg * 8 + hl;  // 16B chunk index within half-row
      *(bf16x8*)&att_s[px * 512 + ((chunk ^ (px & 7)) << 3)] = r8;
    }
    __syncthreads();
    bf16_t* dst = qnT + (size_t)n0 * 1024 + grp * 512;
    for (int i = tid; i < 2048; i += 256) {
      const int r = i >> 6, cc = i & 63;
      bf16x8 v = *(const bf16x8*)&att_s[r * 512 + (((cc ^ (r & 7))) << 3)];
      *(bf16x8*)&dst[(size_t)r * 1024 + cc * 8] = v;
    }
  }
}

// ---------------- launch ----------------
extern "C" void kernel_launch(void* const* d_in, const int* in_sizes, int n_in,
                              void* d_out, int out_size, void* d_ws, size_t ws_size,
                              hipStream_t stream) {
  if (ws_size < WS_NEEDED) return;  // need ~156 MB scratch
  const float* x      = (const float*)d_in[0];
  const float* w_qkv  = (const float*)d_in[1];
  const float* w_dw   = (const float*)d_in[2];
  const float* w_pw   = (const float*)d_in[3];
  const float* w_proj = (const float*)d_in[4];
  const float* gam    = (const float*)d_in[5];
  const float* bet    = (const float*)d_in[6];
  const float* mu     = (const float*)d_in[7];
  const float* va     = (const float*)d_in[8];

  char* w = (char*)d_ws;
  h16*    Qb   = (h16*)(w + OFF_QB);
  h16*    Qr   = (h16*)(w + OFF_QR);
  h16*    KV   = (h16*)(w + OFF_KV);
  h16*    yb   = (h16*)(w + OFF_Y);
  bf16_t* xTh  = (bf16_t*)(w + OFF_XTH);  // aliased with qnT (dead after K1)
  bf16_t* xTl  = (bf16_t*)(w + OFF_XTL);
  bf16_t* qnT  = (bf16_t*)(w + OFF_ATT);
  bf16_t* wqA  = (bf16_t*)(w + OFF_WQA);
  bf16_t* wkv  = (bf16_t*)(w + OFF_WKV);
  bf16_t* wpb  = (bf16_t*)(w + OFF_WP);
  bf16_t* W2   = (bf16_t*)(w + OFF_W2);
  float*  vk   = (float*)(w + OFF_VK);
  float*  part = (float*)(w + OFF_VKP);
  float*  bna  = (float*)(w + OFF_BNA);
  float*  zp   = (float*)(w + OFF_ZP);

  dim3 blk(256);
  // weights + BN fold + zero page (once)
  prep_kernel<<<dim3((PREP_TOT + 255) / 256), blk, 0, stream>>>(
      w_qkv, w_proj, gam, bet, mu, va, wqA, wkv, wpb, bna, zp);

  for (int b = 0; b < 2; ++b) {
    const float* xb = x + (size_t)b * 512 * N_PIX;
    float* outb = (float*)d_out + (size_t)b * 512 * N_PIX;
    // K0a: x -> xT hi/lo bf16
    xpose_kernel<<<dim3(512, 16), blk, 0, stream>>>(xb, xTh, xTl);
    // K1: merged q (3-term via K=1536) + kv GEMM -> Qb/Qr/KV f16
    gemm_qkv_kernel<<<dim3(128, 12), blk, 0, stream>>>(wqA, wkv, xTh, xTl, Qb, Qr, KV);
    // K2: fused dw 5x5 + grouped pw -> y f16 (packed f16 math)
    dwpw_kernel<<<dim3(16, 192), blk, 0, stream>>>(Qb, KV, w_dw, w_pw, (const h16*)zp, yb);
    // K3: vk accumulation (partials, deterministic reduce, W2 fold)
    vk_partial_kernel<<<dim3(8, 128), blk, 0, stream>>>(KV, yb, part);
    vk_reduce_kernel<<<dim3(128), dim3(128), 0, stream>>>(part, vk);
    w2_kernel<<<dim3(512 * 1024 / 256), blk, 0, stream>>>(wpb, vk, W2);
    // K4: qn = relu(q)/den -> qnT
    qn_kernel<<<dim3(512), blk, 0, stream>>>(Qr, yb, vk, qnT);
    // K5: out = W2 x qnT + bna (M=512, K=1024), f32 out
    gemm_proj_kernel<<<dim3(128, 4), blk, 0, stream>>>(W2, qnT, outb, bna);
  }
}